// Round 1
// 920.997 us; speedup vs baseline: 1.0099x; 1.0099x over previous
//
#include <hip/hip_runtime.h>
#include <math.h>

// Problem: x[B=8, C=256, H=256, W=256] fp32; db8 (16-tap) LL-DWT mean ->
// SE-MLP gate -> rescale. LL mean is linear in x: mean = a^T X a / 135^2 with
// a[256] precomputed on host (filter taps folded through symmetric padding).
//
// Structure (this round): batch-chunked fused pipeline for Infinity-Cache
// reuse. One batch of x is 64 MB << 256 MB L3. Launch b runs
//   blocks [0,1024):      reduce(b+1)  -- 4 blocks/channel, 64 rows each
//   blocks [1024,3072):   scale(b)     -- re-reads batch b (L3-resident from
//                                         the previous launch's reduce),
//                                         MLP recomputed per block (cheap),
//                                         NT-stores out (never re-read, keep
//                                         it from evicting x in cache)
// 9 launches total: R(0), 7x fused, S(7).

#define BATCH 8
#define CH    256
#define HW    256
#define LL    135                     // (256+15)//2

typedef float vf4 __attribute__((ext_vector_type(4)));

struct AVec { float a[256]; };

// nred: number of reduce-role blocks (1024 or 0). breduce: batch being
// reduced. bscale: batch being scaled (-1 => no scale blocks in grid).
__global__ __launch_bounds__(256) void wa_fused(
    const float* __restrict__ x, const float* __restrict__ W1,
    const float* __restrict__ W2, float* __restrict__ out,
    float* __restrict__ s_part, AVec av, int breduce, int bscale, int nred)
{
    const int t = threadIdx.x;
    __shared__ float ysh[256];
    __shared__ float hsh[16];
    __shared__ float wsum[4];

    if ((int)blockIdx.x < nred) {
        // ---- reduce role: partial bilinear sum over 64 rows of one slice ---
        const int c   = blockIdx.x >> 2;      // channel
        const int sub = blockIdx.x & 3;       // 64-row chunk
        const float4* __restrict__ xr =
            (const float4*)(x + (((size_t)(breduce * CH + c)) << 16));
        const int cg = t & 63;                // column group (4 cols)
        const int rg = t >> 6;                // wave id -> 16-row window
        const int r0 = sub * 64 + rg * 16;
        float4 acc = make_float4(0.f, 0.f, 0.f, 0.f);
        #pragma unroll 4
        for (int i = r0; i < r0 + 16; ++i) {
            float4 v = xr[(size_t)i * 64 + cg];     // coalesced 1 KB/row/wave
            const float ai = av.a[i];               // wave-uniform
            acc.x = fmaf(ai, v.x, acc.x);
            acc.y = fmaf(ai, v.y, acc.y);
            acc.z = fmaf(ai, v.z, acc.z);
            acc.w = fmaf(ai, v.w, acc.w);
        }
        float partial = acc.x * av.a[4*cg+0] + acc.y * av.a[4*cg+1]
                      + acc.z * av.a[4*cg+2] + acc.w * av.a[4*cg+3];
        #pragma unroll
        for (int off = 32; off > 0; off >>= 1)
            partial += __shfl_down(partial, off, 64);
        if (cg == 0) wsum[rg] = partial;
        __syncthreads();
        if (t == 0)
            s_part[(breduce & 1) * 1024 + c * 4 + sub] =
                wsum[0] + wsum[1] + wsum[2] + wsum[3];
        return;
    }

    // ---- scale role: redundant per-block SE-MLP, then gate 32 KB of x -----
    const int sb = blockIdx.x - nred;         // 0..2047 within batch
    const float* __restrict__ sp = s_part + (bscale & 1) * 1024;
    ysh[t] = (sp[t*4+0] + sp[t*4+1] + sp[t*4+2] + sp[t*4+3])
             * (1.0f / (135.0f * 135.0f));
    __syncthreads();
    // h[j] = relu(sum_k y[k] W1[j,k]); 16 threads per j, shuffle-reduce.
    const int j = t >> 4, l16 = t & 15;
    float hp = 0.f;
    for (int k = l16; k < 256; k += 16) hp = fmaf(ysh[k], W1[j*256 + k], hp);
    #pragma unroll
    for (int off = 8; off > 0; off >>= 1) hp += __shfl_xor(hp, off, 16);
    if (l16 == 0) hsh[j] = fmaxf(hp, 0.f);
    __syncthreads();
    // This block covers 2048 float4 = 1/8 of one channel -> single gate.
    const int c_s = sb >> 3;
    float g = 0.f;
    #pragma unroll
    for (int jj = 0; jj < 16; ++jj) g = fmaf(hsh[jj], W2[c_s*16 + jj], g);
    g = 1.f / (1.f + expf(-g));

    const vf4* __restrict__ x4 = (const vf4*)x;
    vf4* __restrict__ o4 = (vf4*)out;
    const size_t base4 = ((size_t)bscale << 22)     // batch * 4194304 float4
                       + ((size_t)sb << 11) + t;    // block * 2048 + lane
    #pragma unroll
    for (int k = 0; k < 8; ++k) {
        const size_t i = base4 + ((size_t)k << 8);  // stride 256 -> coalesced
        vf4 v = x4[i];
        v *= g;
        __builtin_nontemporal_store(v, o4 + i);     // don't pollute caches
    }
}

extern "C" void kernel_launch(void* const* d_in, const int* in_sizes, int n_in,
                              void* d_out, int out_size, void* d_ws, size_t ws_size,
                              hipStream_t stream) {
    const float* x  = (const float*)d_in[0];   // [8,256,256,256]
    const float* W1 = (const float*)d_in[1];   // [16,256]
    const float* W2 = (const float*)d_in[2];   // [256,16]
    float* out = (float*)d_out;                // [8,256,256,256]
    float* s_part = (float*)d_ws;              // 2 slots x [256 ch][4 sub]

    // Host-side: fold the 135 stride-2 output taps (symmetric padding) into a
    // single per-axis weight vector a[256]. Same values every call -> safe
    // under graph capture (baked into kernel args).
    static const double DB8[16] = {
        -0.00011747678400228192, 0.0006754494059985568, -0.0003917403729959771,
        -0.00487035299301066, 0.008746094047015655, 0.013981027917015516,
        -0.04408825393106472, -0.01736930100202211, 0.128747426620186,
        0.00047248457399797254, -0.2840155429624281, -0.015829105256023893,
        0.5853546836548691, 0.6756307362980128, 0.3128715909144659,
        0.05441584224308161};
    double tmp[256];
    for (int jj = 0; jj < 256; ++jj) tmp[jj] = 0.0;
    // y[m] = sum_t filt[15-t] * xe[2m+t]; xe[s] = p[s+1]; p[t] = x[sym(t-15)]
    // => original index i = 2m + t - 14; sym: i<0 -> -1-i, i>=256 -> 511-i.
    for (int m = 0; m < LL; ++m) {
        for (int tt = 0; tt < 16; ++tt) {
            int i = 2 * m + tt - 14;
            int jj = (i < 0) ? (-1 - i) : ((i >= 256) ? (511 - i) : i);
            tmp[jj] += DB8[15 - tt];
        }
    }
    AVec av;
    for (int jj = 0; jj < 256; ++jj) av.a[jj] = (float)tmp[jj];

    // Pipeline: launch b does reduce(b) and scale(b-1).
    for (int b = 0; b <= BATCH; ++b) {
        const int nred = (b < BATCH) ? 1024 : 0;
        const int nsc  = (b >= 1)    ? 2048 : 0;
        if (nred + nsc == 0) continue;
        wa_fused<<<nred + nsc, 256, 0, stream>>>(
            x, W1, W2, out, s_part, av, b, b - 1, nred);
    }
}